// Round 1
// baseline (1556.442 us; speedup 1.0000x reference)
//
#include <hip/hip_runtime.h>

#define N_V  20000
#define B_   8
#define F_   64
#define K_   6
#define OUT_ 64
#define NNZ_ 320000
#define BF   512   // B_*F_

// ---------------- CSR build ----------------

__global__ void hist_kernel(const int* __restrict__ rows, int* __restrict__ counts) {
    int e = blockIdx.x * 256 + threadIdx.x;
    if (e < NNZ_) atomicAdd(&counts[rows[e]], 1);
}

__global__ __launch_bounds__(1024) void scan_kernel(const int* __restrict__ counts,
                                                    int* __restrict__ row_ptr,
                                                    int* __restrict__ cursor) {
    __shared__ int buf[1024];
    int tid = threadIdx.x;
    if (tid == 0) row_ptr[0] = 0;
    int carry = 0;
    for (int base = 0; base < N_V; base += 1024) {
        int i = base + tid;
        int c = (i < N_V) ? counts[i] : 0;
        buf[tid] = c;
        __syncthreads();
        for (int off = 1; off < 1024; off <<= 1) {
            int t = buf[tid];
            int add = (tid >= off) ? buf[tid - off] : 0;
            __syncthreads();
            buf[tid] = t + add;
            __syncthreads();
        }
        int incl = buf[tid];
        if (i < N_V) {
            row_ptr[i + 1] = carry + incl;
            cursor[i] = carry + incl - c;   // exclusive prefix
        }
        int total = buf[1023];
        carry += total;
        __syncthreads();   // protect buf before next iteration's write
    }
}

__global__ void scatter_kernel(const int* __restrict__ rows, const int* __restrict__ cols,
                               const float* __restrict__ vals, int* __restrict__ cursor,
                               int* __restrict__ cols_perm, float* __restrict__ vals_perm) {
    int e = blockIdx.x * 256 + threadIdx.x;
    if (e < NNZ_) {
        int r = rows[e];
        int pos = atomicAdd(&cursor[r], 1);
        cols_perm[pos] = cols[e];
        vals_perm[pos] = vals[e];
    }
}

// ---------------- Chebyshev SpMM ----------------
// MODE 0: T1 = L @ T0            (prev = x virtual, no subtract)
// MODE 1: T2 = 2 L T1 - T0       (prev = buffer, subtract x virtual)
// MODE 2: Tk = 2 L Tk-1 - Tk-2   (all buffers)
template <int MODE>
__global__ __launch_bounds__(512) void cheb_spmm(const int* __restrict__ row_ptr,
                                                 const int* __restrict__ cols_perm,
                                                 const float* __restrict__ vals_perm,
                                                 const float* __restrict__ x,
                                                 const float* __restrict__ Tprev,
                                                 const float* __restrict__ Tpp,
                                                 float* __restrict__ Tout) {
    int n = blockIdx.x;
    int t = threadIdx.x;             // 0..511
    int b = t >> 6, f = t & 63;
    size_t xb = (size_t)b * N_V * F_;
    int start = row_ptr[n], end = row_ptr[n + 1];
    float acc = 0.f;
    for (int j = start; j < end; ++j) {
        int   c = cols_perm[j];
        float v = vals_perm[j];
        float xv = (MODE == 0) ? x[xb + (size_t)c * F_ + f]
                               : Tprev[(size_t)c * BF + t];
        acc = fmaf(v, xv, acc);
    }
    float res;
    if (MODE == 0)      res = acc;
    else if (MODE == 1) res = 2.f * acc - x[xb + (size_t)n * F_ + f];
    else                res = 2.f * acc - Tpp[(size_t)n * BF + t];
    Tout[(size_t)n * BF + t] = res;
}

// ---------------- FC accumulation: out += T_k @ W_k^T ----------------
// One wave per (n,b) row; lane = output channel o.
template <bool INIT, bool T_IS_X>
__global__ __launch_bounds__(256) void fc_kernel(const float* __restrict__ T,
                                                 const float* __restrict__ W,
                                                 const float* __restrict__ bias,
                                                 float* __restrict__ out, int k) {
    __shared__ float wk[64 * 64];            // wk[f*64 + o] = W[o, k*64+f]
    int tid = threadIdx.x;
    for (int i = tid; i < 4096; i += 256) {
        int f = i >> 6, o = i & 63;
        wk[i] = W[o * (K_ * F_) + k * 64 + f];
    }
    __syncthreads();
    int wave = tid >> 6, lane = tid & 63;
    for (int row = blockIdx.x * 4 + wave; row < N_V * B_; row += gridDim.x * 4) {
        int n = row >> 3, b = row & 7;       // row = n*B + b
        float tv = T_IS_X ? T[(size_t)b * N_V * F_ + (size_t)n * F_ + lane]
                          : T[(size_t)n * BF + b * 64 + lane];
        float acc = 0.f;
        #pragma unroll
        for (int f = 0; f < 64; ++f) {
            acc = fmaf(__shfl(tv, f, 64), wk[f * 64 + lane], acc);
        }
        size_t oidx = (size_t)b * N_V * OUT_ + (size_t)n * OUT_ + lane;
        if (INIT) out[oidx] = acc + bias[lane];
        else      out[oidx] += acc;
    }
}

// ---------------- launcher ----------------

extern "C" void kernel_launch(void* const* d_in, const int* in_sizes, int n_in,
                              void* d_out, int out_size, void* d_ws, size_t ws_size,
                              hipStream_t stream) {
    const float* x    = (const float*)d_in[0];
    const int*   rows = (const int*)  d_in[1];
    const int*   cols = (const int*)  d_in[2];
    const float* vals = (const float*)d_in[3];
    const float* W    = (const float*)d_in[4];
    const float* bias = (const float*)d_in[5];
    float* out = (float*)d_out;

    const size_t TSZ = (size_t)N_V * BF;     // 10,240,000 floats
    float* TA = (float*)d_ws;
    float* TB = TA + TSZ;
    float* TC = TB + TSZ;
    int* counts    = (int*)(TC + TSZ);
    int* row_ptr   = counts + 20032;
    int* cursor    = row_ptr + 20032;
    int* cols_perm = cursor + 20032;
    float* vals_perm = (float*)(cols_perm + NNZ_);

    hipMemsetAsync(counts, 0, N_V * sizeof(int), stream);
    hist_kernel<<<(NNZ_ + 255) / 256, 256, 0, stream>>>(rows, counts);
    scan_kernel<<<1, 1024, 0, stream>>>(counts, row_ptr, cursor);
    scatter_kernel<<<(NNZ_ + 255) / 256, 256, 0, stream>>>(rows, cols, vals, cursor,
                                                           cols_perm, vals_perm);

    const int FCG = 2048;
    // k=0 : T0 (virtual, = x), init out with bias
    fc_kernel<true, true><<<FCG, 256, 0, stream>>>(x, W, bias, out, 0);
    // k=1 : T1 = L T0
    cheb_spmm<0><<<N_V, 512, 0, stream>>>(row_ptr, cols_perm, vals_perm, x, nullptr, nullptr, TA);
    fc_kernel<false, false><<<FCG, 256, 0, stream>>>(TA, W, bias, out, 1);
    // k=2 : T2 = 2 L T1 - T0
    cheb_spmm<1><<<N_V, 512, 0, stream>>>(row_ptr, cols_perm, vals_perm, x, TA, nullptr, TB);
    fc_kernel<false, false><<<FCG, 256, 0, stream>>>(TB, W, bias, out, 2);
    // k=3
    cheb_spmm<2><<<N_V, 512, 0, stream>>>(row_ptr, cols_perm, vals_perm, x, TB, TA, TC);
    fc_kernel<false, false><<<FCG, 256, 0, stream>>>(TC, W, bias, out, 3);
    // k=4
    cheb_spmm<2><<<N_V, 512, 0, stream>>>(row_ptr, cols_perm, vals_perm, x, TC, TB, TA);
    fc_kernel<false, false><<<FCG, 256, 0, stream>>>(TA, W, bias, out, 4);
    // k=5
    cheb_spmm<2><<<N_V, 512, 0, stream>>>(row_ptr, cols_perm, vals_perm, x, TA, TC, TB);
    fc_kernel<false, false><<<FCG, 256, 0, stream>>>(TB, W, bias, out, 5);
}

// Round 2
// 816.871 us; speedup vs baseline: 1.9054x; 1.9054x over previous
//
#include <hip/hip_runtime.h>

#define N_V  20000
#define B_   8
#define F_   64
#define K_   6
#define OUT_ 64
#define NNZ_ 320000
#define BF   512   // B_*F_

// ---------------- CSR build ----------------

__global__ void hist_kernel(const int* __restrict__ rows, int* __restrict__ counts) {
    int e = blockIdx.x * 256 + threadIdx.x;
    if (e < NNZ_) atomicAdd(&counts[rows[e]], 1);
}

__global__ __launch_bounds__(1024) void scan_kernel(const int* __restrict__ counts,
                                                    int* __restrict__ row_ptr,
                                                    int* __restrict__ cursor) {
    __shared__ int buf[1024];
    int tid = threadIdx.x;
    if (tid == 0) row_ptr[0] = 0;
    int carry = 0;
    for (int base = 0; base < N_V; base += 1024) {
        int i = base + tid;
        int c = (i < N_V) ? counts[i] : 0;
        buf[tid] = c;
        __syncthreads();
        for (int off = 1; off < 1024; off <<= 1) {
            int t = buf[tid];
            int add = (tid >= off) ? buf[tid - off] : 0;
            __syncthreads();
            buf[tid] = t + add;
            __syncthreads();
        }
        int incl = buf[tid];
        if (i < N_V) {
            row_ptr[i + 1] = carry + incl;
            cursor[i] = carry + incl - c;   // exclusive prefix
        }
        int total = buf[1023];
        carry += total;
        __syncthreads();
    }
}

__global__ void scatter_kernel(const int* __restrict__ rows, const int* __restrict__ cols,
                               const float* __restrict__ vals, int* __restrict__ cursor,
                               int* __restrict__ cols_perm, float* __restrict__ vals_perm) {
    int e = blockIdx.x * 256 + threadIdx.x;
    if (e < NNZ_) {
        int r = rows[e];
        int pos = atomicAdd(&cursor[r], 1);
        cols_perm[pos] = cols[e];
        vals_perm[pos] = vals[e];
    }
}

// ---------------- Chebyshev SpMM (ILP-8 gather) ----------------
// MODE 0: T1 = L @ x           MODE 1: T2 = 2 L T1 - x        MODE 2: Tk = 2 L Tk-1 - Tk-2
template <int MODE>
__global__ __launch_bounds__(512) void cheb_spmm(const int* __restrict__ row_ptr,
                                                 const int* __restrict__ cols_perm,
                                                 const float* __restrict__ vals_perm,
                                                 const float* __restrict__ x,
                                                 const float* __restrict__ Tprev,
                                                 const float* __restrict__ Tpp,
                                                 float* __restrict__ Tout) {
    int n = blockIdx.x;
    int t = threadIdx.x;             // 0..511
    int b = t >> 6, f = t & 63;
    size_t xb = (size_t)b * N_V * F_;
    int start = row_ptr[n], end = row_ptr[n + 1];
    float acc = 0.f;
    // 8-wide chunks with masked tail: 8 independent gathers in flight.
    for (int j = start; j < end; j += 8) {
        int   c[8];
        float v[8];
#pragma unroll
        for (int i = 0; i < 8; ++i) {
            int jj = j + i;
            int jc = jj < (NNZ_ - 1) ? jj : (NNZ_ - 1);   // clamp: no OOB load
            int   cc = cols_perm[jc];
            float vv = vals_perm[jc];
            c[i] = cc;
            v[i] = (jj < end) ? vv : 0.f;                  // mask tail
        }
#pragma unroll
        for (int i = 0; i < 8; ++i) {
            float xv = (MODE == 0) ? x[xb + (size_t)c[i] * F_ + f]
                                   : Tprev[(size_t)c[i] * BF + t];
            acc = fmaf(v[i], xv, acc);
        }
    }
    float res;
    if (MODE == 0)      res = acc;
    else if (MODE == 1) res = 2.f * acc - x[xb + (size_t)n * F_ + f];
    else                res = 2.f * acc - Tpp[(size_t)n * BF + t];
    Tout[(size_t)n * BF + t] = res;
}

// ---------------- W pre-transpose: Wt[kf*64 + o] = W[o*384 + kf] ----------------
__global__ void wt_kernel(const float* __restrict__ W, float* __restrict__ Wt) {
    int idx = blockIdx.x * 256 + threadIdx.x;   // 0..24575
    if (idx < K_ * F_ * OUT_) {
        int o = idx / (K_ * F_);
        int kf = idx - o * (K_ * F_);
        Wt[kf * OUT_ + o] = W[idx];
    }
}

// ---------------- Final FC GEMM: out[b,n,o] = sum_k sum_f Tk[n,b,f] * W[o,k*64+f] + bias ----
// Block: 64 rows (8 n x 8 b) x 64 outs. Thread: 4x4 register tile.
#define LDA 68   // pad: 16B-aligned rows (68*4=272=17*16), bank-conflict-free
__global__ __launch_bounds__(256) void fc_gemm(const float* __restrict__ x,
                                               const float* __restrict__ T1,
                                               const float* __restrict__ T2,
                                               const float* __restrict__ T3,
                                               const float* __restrict__ T4,
                                               const float* __restrict__ T5,
                                               const float* __restrict__ Wt,
                                               const float* __restrict__ bias,
                                               float* __restrict__ out) {
    __shared__ float As[64 * LDA];
    __shared__ float Ws[64 * 64];
    const int t  = threadIdx.x;
    const int tx = t & 15;          // col group: o = tx*4 + j
    const int ty = t >> 4;          // row group: r = ty*4 + i
    const int n0 = blockIdx.x * 8;  // 8 n per block -> 64 (n,b) rows
    const float* Tb[5] = {T1, T2, T3, T4, T5};
    float acc[4][4] = {{0.f}};
#pragma unroll
    for (int k = 0; k < K_; ++k) {
        // ---- stage A tile (64 rows x 64 f), float4, row r=(n-n0)*8+b ----
        if (k == 0) {
#pragma unroll
            for (int it = 0; it < 4; ++it) {
                int idx4 = t + it * 256;          // 0..1023
                int idx  = idx4 * 4;
                int r = idx >> 6, fq = idx & 63;
                const float4 v = *(const float4*)&x[(size_t)(r & 7) * N_V * F_
                                                    + (size_t)(n0 + (r >> 3)) * F_ + fq];
                *(float4*)&As[r * LDA + fq] = v;
            }
        } else {
            const float4* src = (const float4*)(Tb[k - 1] + (size_t)n0 * BF);
#pragma unroll
            for (int it = 0; it < 4; ++it) {
                int idx4 = t + it * 256;
                float4 v = src[idx4];
                int idx = idx4 * 4;
                int r = idx >> 6, fq = idx & 63;
                *(float4*)&As[r * LDA + fq] = v;
            }
        }
        // ---- stage W tile (64 f x 64 o) from pre-transposed Wt ----
        {
            const float4* wsrc = (const float4*)(Wt + k * 4096);
#pragma unroll
            for (int it = 0; it < 4; ++it) {
                int idx4 = t + it * 256;
                *(float4*)&Ws[idx4 * 4] = wsrc[idx4];
            }
        }
        __syncthreads();
        // ---- 4x4 register-tile inner product over this 64-chunk of f ----
#pragma unroll 8
        for (int ff = 0; ff < 64; ++ff) {
            float4 w = *(const float4*)&Ws[ff * 64 + tx * 4];
            float a0 = As[(ty * 4 + 0) * LDA + ff];
            float a1 = As[(ty * 4 + 1) * LDA + ff];
            float a2 = As[(ty * 4 + 2) * LDA + ff];
            float a3 = As[(ty * 4 + 3) * LDA + ff];
            acc[0][0] = fmaf(a0, w.x, acc[0][0]);
            acc[0][1] = fmaf(a0, w.y, acc[0][1]);
            acc[0][2] = fmaf(a0, w.z, acc[0][2]);
            acc[0][3] = fmaf(a0, w.w, acc[0][3]);
            acc[1][0] = fmaf(a1, w.x, acc[1][0]);
            acc[1][1] = fmaf(a1, w.y, acc[1][1]);
            acc[1][2] = fmaf(a1, w.z, acc[1][2]);
            acc[1][3] = fmaf(a1, w.w, acc[1][3]);
            acc[2][0] = fmaf(a2, w.x, acc[2][0]);
            acc[2][1] = fmaf(a2, w.y, acc[2][1]);
            acc[2][2] = fmaf(a2, w.z, acc[2][2]);
            acc[2][3] = fmaf(a2, w.w, acc[2][3]);
            acc[3][0] = fmaf(a3, w.x, acc[3][0]);
            acc[3][1] = fmaf(a3, w.y, acc[3][1]);
            acc[3][2] = fmaf(a3, w.z, acc[3][2]);
            acc[3][3] = fmaf(a3, w.w, acc[3][3]);
        }
        __syncthreads();
    }
    const float4 b4 = *(const float4*)&bias[tx * 4];
#pragma unroll
    for (int i = 0; i < 4; ++i) {
        int r = ty * 4 + i;
        int nn = n0 + (r >> 3), bb = r & 7;
        float4 o;
        o.x = acc[i][0] + b4.x;
        o.y = acc[i][1] + b4.y;
        o.z = acc[i][2] + b4.z;
        o.w = acc[i][3] + b4.w;
        *(float4*)&out[(size_t)bb * N_V * OUT_ + (size_t)nn * OUT_ + tx * 4] = o;
    }
}

// ---------------- fallback per-k FC (round-1 proven path) ----------------
template <bool INIT, bool T_IS_X>
__global__ __launch_bounds__(256) void fc_kernel(const float* __restrict__ T,
                                                 const float* __restrict__ W,
                                                 const float* __restrict__ bias,
                                                 float* __restrict__ out, int k) {
    __shared__ float wk[64 * 64];
    int tid = threadIdx.x;
    for (int i = tid; i < 4096; i += 256) {
        int f = i >> 6, o = i & 63;
        wk[i] = W[o * (K_ * F_) + k * 64 + f];
    }
    __syncthreads();
    int wave = tid >> 6, lane = tid & 63;
    for (int row = blockIdx.x * 4 + wave; row < N_V * B_; row += gridDim.x * 4) {
        int n = row >> 3, b = row & 7;
        float tv = T_IS_X ? T[(size_t)b * N_V * F_ + (size_t)n * F_ + lane]
                          : T[(size_t)n * BF + b * 64 + lane];
        float acc = 0.f;
#pragma unroll
        for (int f = 0; f < 64; ++f) {
            acc = fmaf(__shfl(tv, f, 64), wk[f * 64 + lane], acc);
        }
        size_t oidx = (size_t)b * N_V * OUT_ + (size_t)n * OUT_ + lane;
        if (INIT) out[oidx] = acc + bias[lane];
        else      out[oidx] += acc;
    }
}

// ---------------- launcher ----------------

extern "C" void kernel_launch(void* const* d_in, const int* in_sizes, int n_in,
                              void* d_out, int out_size, void* d_ws, size_t ws_size,
                              hipStream_t stream) {
    const float* x    = (const float*)d_in[0];
    const int*   rows = (const int*)  d_in[1];
    const int*   cols = (const int*)  d_in[2];
    const float* vals = (const float*)d_in[3];
    const float* W    = (const float*)d_in[4];
    const float* bias = (const float*)d_in[5];
    float* out = (float*)d_out;

    const size_t TSZ = (size_t)N_V * BF;      // 10,240,000 floats per T buffer
    const size_t need5 = (5 * TSZ + 24576 + 3 * 20032 + 2 * (size_t)NNZ_) * sizeof(float);

    if (ws_size >= need5) {
        float* T1 = (float*)d_ws;
        float* T2 = T1 + TSZ;
        float* T3 = T2 + TSZ;
        float* T4 = T3 + TSZ;
        float* T5 = T4 + TSZ;
        float* Wt = T5 + TSZ;
        int* counts    = (int*)(Wt + 24576);
        int* row_ptr   = counts + 20032;
        int* cursor    = row_ptr + 20032;
        int* cols_perm = cursor + 20032;
        float* vals_perm = (float*)(cols_perm + NNZ_);

        hipMemsetAsync(counts, 0, N_V * sizeof(int), stream);
        hist_kernel<<<(NNZ_ + 255) / 256, 256, 0, stream>>>(rows, counts);
        scan_kernel<<<1, 1024, 0, stream>>>(counts, row_ptr, cursor);
        scatter_kernel<<<(NNZ_ + 255) / 256, 256, 0, stream>>>(rows, cols, vals, cursor,
                                                               cols_perm, vals_perm);
        wt_kernel<<<96, 256, 0, stream>>>(W, Wt);

        cheb_spmm<0><<<N_V, 512, 0, stream>>>(row_ptr, cols_perm, vals_perm, x, nullptr, nullptr, T1);
        cheb_spmm<1><<<N_V, 512, 0, stream>>>(row_ptr, cols_perm, vals_perm, x, T1, nullptr, T2);
        cheb_spmm<2><<<N_V, 512, 0, stream>>>(row_ptr, cols_perm, vals_perm, x, T2, T1, T3);
        cheb_spmm<2><<<N_V, 512, 0, stream>>>(row_ptr, cols_perm, vals_perm, x, T3, T2, T4);
        cheb_spmm<2><<<N_V, 512, 0, stream>>>(row_ptr, cols_perm, vals_perm, x, T4, T3, T5);

        fc_gemm<<<N_V * B_ / 64, 256, 0, stream>>>(x, T1, T2, T3, T4, T5, Wt, bias, out);
    } else {
        // fallback: 3-buffer rotation + per-k accumulate (round-1 path)
        float* TA = (float*)d_ws;
        float* TB = TA + TSZ;
        float* TC = TB + TSZ;
        int* counts    = (int*)(TC + TSZ);
        int* row_ptr   = counts + 20032;
        int* cursor    = row_ptr + 20032;
        int* cols_perm = cursor + 20032;
        float* vals_perm = (float*)(cols_perm + NNZ_);

        hipMemsetAsync(counts, 0, N_V * sizeof(int), stream);
        hist_kernel<<<(NNZ_ + 255) / 256, 256, 0, stream>>>(rows, counts);
        scan_kernel<<<1, 1024, 0, stream>>>(counts, row_ptr, cursor);
        scatter_kernel<<<(NNZ_ + 255) / 256, 256, 0, stream>>>(rows, cols, vals, cursor,
                                                               cols_perm, vals_perm);
        const int FCG = 2048;
        fc_kernel<true, true><<<FCG, 256, 0, stream>>>(x, W, bias, out, 0);
        cheb_spmm<0><<<N_V, 512, 0, stream>>>(row_ptr, cols_perm, vals_perm, x, nullptr, nullptr, TA);
        fc_kernel<false, false><<<FCG, 256, 0, stream>>>(TA, W, bias, out, 1);
        cheb_spmm<1><<<N_V, 512, 0, stream>>>(row_ptr, cols_perm, vals_perm, x, TA, nullptr, TB);
        fc_kernel<false, false><<<FCG, 256, 0, stream>>>(TB, W, bias, out, 2);
        cheb_spmm<2><<<N_V, 512, 0, stream>>>(row_ptr, cols_perm, vals_perm, x, TB, TA, TC);
        fc_kernel<false, false><<<FCG, 256, 0, stream>>>(TC, W, bias, out, 3);
        cheb_spmm<2><<<N_V, 512, 0, stream>>>(row_ptr, cols_perm, vals_perm, x, TC, TB, TA);
        fc_kernel<false, false><<<FCG, 256, 0, stream>>>(TA, W, bias, out, 4);
        cheb_spmm<2><<<N_V, 512, 0, stream>>>(row_ptr, cols_perm, vals_perm, x, TA, TC, TB);
        fc_kernel<false, false><<<FCG, 256, 0, stream>>>(TB, W, bias, out, 5);
    }
}

// Round 3
// 499.890 us; speedup vs baseline: 3.1136x; 1.6341x over previous
//
#include <hip/hip_runtime.h>

#define N_V  20000
#define B_   8
#define F_   64
#define K_   6
#define OUT_ 64
#define NNZ_ 320000
#define BF   512   // B_*F_

typedef unsigned short ushort_t;
typedef unsigned int   uint_t;

using frag_ab = __attribute__((ext_vector_type(8))) short;  // 8 bf16 (4 VGPRs)
using frag_cd = __attribute__((ext_vector_type(4))) float;  // 4 f32 acc

// ---- bf16 helpers ----
__device__ __forceinline__ ushort_t f2bf(float f) {          // round-to-nearest-even
    uint_t u = __float_as_uint(f);
    u += 0x7FFFu + ((u >> 16) & 1u);
    return (ushort_t)(u >> 16);
}
__device__ __forceinline__ uint_t pack2(float lo, float hi) {
    return (uint_t)f2bf(lo) | ((uint_t)f2bf(hi) << 16);
}
__device__ __forceinline__ void unpack2(uint_t u, float& lo, float& hi) {
    lo = __uint_as_float(u << 16);
    hi = __uint_as_float(u & 0xFFFF0000u);
}

// ---------------- CSR build ----------------

__global__ void hist_kernel(const int* __restrict__ rows, int* __restrict__ counts) {
    int e = blockIdx.x * 256 + threadIdx.x;
    if (e < NNZ_) atomicAdd(&counts[rows[e]], 1);
}

__global__ __launch_bounds__(1024) void scan_kernel(const int* __restrict__ counts,
                                                    int* __restrict__ row_ptr,
                                                    int* __restrict__ cursor) {
    __shared__ int buf[1024];
    int tid = threadIdx.x;
    if (tid == 0) row_ptr[0] = 0;
    int carry = 0;
    for (int base = 0; base < N_V; base += 1024) {
        int i = base + tid;
        int c = (i < N_V) ? counts[i] : 0;
        buf[tid] = c;
        __syncthreads();
        for (int off = 1; off < 1024; off <<= 1) {
            int t = buf[tid];
            int add = (tid >= off) ? buf[tid - off] : 0;
            __syncthreads();
            buf[tid] = t + add;
            __syncthreads();
        }
        int incl = buf[tid];
        if (i < N_V) {
            row_ptr[i + 1] = carry + incl;
            cursor[i] = carry + incl - c;   // exclusive prefix
        }
        int total = buf[1023];
        carry += total;
        __syncthreads();
    }
}

__global__ void scatter_kernel(const int* __restrict__ rows, const int* __restrict__ cols,
                               const float* __restrict__ vals, int* __restrict__ cursor,
                               int* __restrict__ cols_perm, float* __restrict__ vals_perm) {
    int e = blockIdx.x * 256 + threadIdx.x;
    if (e < NNZ_) {
        int r = rows[e];
        int pos = atomicAdd(&cursor[r], 1);
        cols_perm[pos] = cols[e];
        vals_perm[pos] = vals[e];
    }
}

// ---------------- Chebyshev SpMM, bf16 T storage ----------------
// 1 wave per row n; lane owns 8 contiguous elements of the 512-wide row
// (e = lane*8 .. lane*8+7  ->  b = lane>>3, f = (lane&7)*8 + i).
// MODE 0: T1 = L@x (f32 src)   MODE 1: T2 = 2 L T1 - x   MODE 2: Tk = 2 L Tk-1 - Tk-2
template <int MODE>
__global__ __launch_bounds__(256) void cheb_spmm_bf(const int* __restrict__ row_ptr,
                                                    const int* __restrict__ cols_perm,
                                                    const float* __restrict__ vals_perm,
                                                    const float* __restrict__ x,
                                                    const ushort_t* __restrict__ Tprev,
                                                    const ushort_t* __restrict__ Tpp,
                                                    ushort_t* __restrict__ Tout) {
    const int wave = threadIdx.x >> 6, lane = threadIdx.x & 63;
    const int n = blockIdx.x * 4 + wave;
    const int b = lane >> 3, f0 = (lane & 7) * 8;
    const size_t xrow = (size_t)b * N_V * F_;
    const int start = row_ptr[n], end = row_ptr[n + 1];

    float acc[8];
#pragma unroll
    for (int i = 0; i < 8; ++i) acc[i] = 0.f;

    for (int j = start; j < end; j += 8) {
        int   c[8];
        float v[8];
#pragma unroll
        for (int i = 0; i < 8; ++i) {
            int jj = j + i;
            int jc = jj < (NNZ_ - 1) ? jj : (NNZ_ - 1);
            c[i] = cols_perm[jc];
            float vv = vals_perm[jc];
            v[i] = (jj < end) ? vv : 0.f;
        }
        if (MODE == 0) {
#pragma unroll
            for (int i = 0; i < 8; ++i) {
                const float4* p = (const float4*)(x + xrow + (size_t)c[i] * F_ + f0);
                float4 p0 = p[0], p1 = p[1];
                acc[0] = fmaf(v[i], p0.x, acc[0]);
                acc[1] = fmaf(v[i], p0.y, acc[1]);
                acc[2] = fmaf(v[i], p0.z, acc[2]);
                acc[3] = fmaf(v[i], p0.w, acc[3]);
                acc[4] = fmaf(v[i], p1.x, acc[4]);
                acc[5] = fmaf(v[i], p1.y, acc[5]);
                acc[6] = fmaf(v[i], p1.z, acc[6]);
                acc[7] = fmaf(v[i], p1.w, acc[7]);
            }
        } else {
#pragma unroll
            for (int i = 0; i < 8; ++i) {
                uint4 u = *(const uint4*)(Tprev + (size_t)c[i] * BF + lane * 8);
                float e0, e1, e2, e3, e4, e5, e6, e7;
                unpack2(u.x, e0, e1); unpack2(u.y, e2, e3);
                unpack2(u.z, e4, e5); unpack2(u.w, e6, e7);
                acc[0] = fmaf(v[i], e0, acc[0]);
                acc[1] = fmaf(v[i], e1, acc[1]);
                acc[2] = fmaf(v[i], e2, acc[2]);
                acc[3] = fmaf(v[i], e3, acc[3]);
                acc[4] = fmaf(v[i], e4, acc[4]);
                acc[5] = fmaf(v[i], e5, acc[5]);
                acc[6] = fmaf(v[i], e6, acc[6]);
                acc[7] = fmaf(v[i], e7, acc[7]);
            }
        }
    }

    float res[8];
    if (MODE == 0) {
#pragma unroll
        for (int i = 0; i < 8; ++i) res[i] = acc[i];
    } else if (MODE == 1) {
        const float4* p = (const float4*)(x + xrow + (size_t)n * F_ + f0);
        float4 p0 = p[0], p1 = p[1];
        res[0] = 2.f * acc[0] - p0.x; res[1] = 2.f * acc[1] - p0.y;
        res[2] = 2.f * acc[2] - p0.z; res[3] = 2.f * acc[3] - p0.w;
        res[4] = 2.f * acc[4] - p1.x; res[5] = 2.f * acc[5] - p1.y;
        res[6] = 2.f * acc[6] - p1.z; res[7] = 2.f * acc[7] - p1.w;
    } else {
        uint4 u = *(const uint4*)(Tpp + (size_t)n * BF + lane * 8);
        float e0, e1, e2, e3, e4, e5, e6, e7;
        unpack2(u.x, e0, e1); unpack2(u.y, e2, e3);
        unpack2(u.z, e4, e5); unpack2(u.w, e6, e7);
        res[0] = 2.f * acc[0] - e0; res[1] = 2.f * acc[1] - e1;
        res[2] = 2.f * acc[2] - e2; res[3] = 2.f * acc[3] - e3;
        res[4] = 2.f * acc[4] - e4; res[5] = 2.f * acc[5] - e5;
        res[6] = 2.f * acc[6] - e6; res[7] = 2.f * acc[7] - e7;
    }
    uint4 st;
    st.x = pack2(res[0], res[1]);
    st.y = pack2(res[2], res[3]);
    st.z = pack2(res[4], res[5]);
    st.w = pack2(res[6], res[7]);
    *(uint4*)(Tout + (size_t)n * BF + lane * 8) = st;
}

// ---------------- Wfrag: W packed in MFMA B-fragment lane order ----------------
// Wfrag[((s*4+ct)*64 + lane)*8 + j] = bf16( W[o*384 + kglob] )
//   o = ct*16 + (lane&15),  kglob = s*32 + ((lane>>4)&3)*8 + j
__global__ void wfrag_kernel(const float* __restrict__ W, ushort_t* __restrict__ Wfrag) {
    int idx = blockIdx.x * 256 + threadIdx.x;   // 0..24575
    if (idx < 12 * 4 * 64 * 8) {
        int j    = idx & 7;
        int lane = (idx >> 3) & 63;
        int ct   = (idx >> 9) & 3;
        int s    = idx >> 11;
        int o     = ct * 16 + (lane & 15);
        int kglob = s * 32 + ((lane >> 4) & 3) * 8 + j;
        Wfrag[idx] = f2bf(W[o * (K_ * F_) + kglob]);
    }
}

// ---------------- FC via MFMA 16x16x32 bf16 ----------------
// C[r=n*8+b][o] = sum_k A[r][k]*W[o][k] + bias[o];  A = [x | T1..T5] rows of 384.
// Block: 4 waves, each wave a 16-row x 64-col tile. 12 k-steps x 4 col-tiles = 48 MFMA.
__global__ __launch_bounds__(256) void fc_mfma(const float* __restrict__ x,
                                               const ushort_t* __restrict__ T1,
                                               const ushort_t* __restrict__ T2,
                                               const ushort_t* __restrict__ T3,
                                               const ushort_t* __restrict__ T4,
                                               const ushort_t* __restrict__ T5,
                                               const ushort_t* __restrict__ Wfrag,
                                               const float* __restrict__ bias,
                                               float* __restrict__ out) {
    const int wave = threadIdx.x >> 6, lane = threadIdx.x & 63;
    const int quad = lane >> 4, col = lane & 15;
    const int tb = blockIdx.x * 64 + wave * 16;      // tile row base
    const int r = tb + col;                           // this lane's A row (m = lane&15)
    const int an = r >> 3, ab = r & 7;                // A row -> (n, b)
    const ushort_t* Tbuf[5] = {T1, T2, T3, T4, T5};

    frag_cd acc[4];
#pragma unroll
    for (int ct = 0; ct < 4; ++ct) acc[ct] = (frag_cd){0.f, 0.f, 0.f, 0.f};

#pragma unroll
    for (int s = 0; s < 12; ++s) {
        const int f0 = (s & 1) * 32 + quad * 8;       // k offset within 64-chunk
        frag_ab a;
        if (s < 2) {
            const float4* p = (const float4*)(x + (size_t)ab * N_V * F_ + (size_t)an * F_ + f0);
            float4 p0 = p[0], p1 = p[1];
            a[0] = (short)f2bf(p0.x); a[1] = (short)f2bf(p0.y);
            a[2] = (short)f2bf(p0.z); a[3] = (short)f2bf(p0.w);
            a[4] = (short)f2bf(p1.x); a[5] = (short)f2bf(p1.y);
            a[6] = (short)f2bf(p1.z); a[7] = (short)f2bf(p1.w);
        } else {
            a = *(const frag_ab*)(Tbuf[(s >> 1) - 1] + (size_t)r * F_ + f0);
        }
#pragma unroll
        for (int ct = 0; ct < 4; ++ct) {
            frag_ab bfr = *(const frag_ab*)(Wfrag + (((s * 4 + ct) * 64 + lane) << 3));
            acc[ct] = __builtin_amdgcn_mfma_f32_16x16x32_bf16(a, bfr, acc[ct], 0, 0, 0);
        }
    }

    // C/D: col = lane&15, row = quad*4 + reg
#pragma unroll
    for (int ct = 0; ct < 4; ++ct) {
        const int o = ct * 16 + col;
        const float bv = bias[o];
#pragma unroll
        for (int reg = 0; reg < 4; ++reg) {
            int rr = tb + quad * 4 + reg;
            int nn = rr >> 3, bb = rr & 7;
            out[(size_t)bb * N_V * OUT_ + (size_t)nn * OUT_ + o] = acc[ct][reg] + bv;
        }
    }
}

// ---------------- launcher ----------------

extern "C" void kernel_launch(void* const* d_in, const int* in_sizes, int n_in,
                              void* d_out, int out_size, void* d_ws, size_t ws_size,
                              hipStream_t stream) {
    const float* x    = (const float*)d_in[0];
    const int*   rows = (const int*)  d_in[1];
    const int*   cols = (const int*)  d_in[2];
    const float* vals = (const float*)d_in[3];
    const float* W    = (const float*)d_in[4];
    const float* bias = (const float*)d_in[5];
    float* out = (float*)d_out;

    const size_t TSZ = (size_t)N_V * BF;           // elements per T buffer
    ushort_t* T1 = (ushort_t*)d_ws;
    ushort_t* T2 = T1 + TSZ;
    ushort_t* T3 = T2 + TSZ;
    ushort_t* T4 = T3 + TSZ;
    ushort_t* T5 = T4 + TSZ;
    ushort_t* Wfrag = T5 + TSZ;                    // 24576 ushorts
    int* counts    = (int*)(Wfrag + 24576);
    int* row_ptr   = counts + 20032;
    int* cursor    = row_ptr + 20032;
    int* cols_perm = cursor + 20032;
    float* vals_perm = (float*)(cols_perm + NNZ_);

    hipMemsetAsync(counts, 0, N_V * sizeof(int), stream);
    hist_kernel<<<(NNZ_ + 255) / 256, 256, 0, stream>>>(rows, counts);
    scan_kernel<<<1, 1024, 0, stream>>>(counts, row_ptr, cursor);
    scatter_kernel<<<(NNZ_ + 255) / 256, 256, 0, stream>>>(rows, cols, vals, cursor,
                                                           cols_perm, vals_perm);
    wfrag_kernel<<<96, 256, 0, stream>>>(W, Wfrag);

    cheb_spmm_bf<0><<<N_V / 4, 256, 0, stream>>>(row_ptr, cols_perm, vals_perm, x, nullptr, nullptr, T1);
    cheb_spmm_bf<1><<<N_V / 4, 256, 0, stream>>>(row_ptr, cols_perm, vals_perm, x, T1, nullptr, T2);
    cheb_spmm_bf<2><<<N_V / 4, 256, 0, stream>>>(row_ptr, cols_perm, vals_perm, x, T2, T1, T3);
    cheb_spmm_bf<2><<<N_V / 4, 256, 0, stream>>>(row_ptr, cols_perm, vals_perm, x, T3, T2, T4);
    cheb_spmm_bf<2><<<N_V / 4, 256, 0, stream>>>(row_ptr, cols_perm, vals_perm, x, T4, T3, T5);

    fc_mfma<<<(N_V * B_) / 64, 256, 0, stream>>>(x, T1, T2, T3, T4, T5, Wfrag, bias, out);
}

// Round 4
// 430.818 us; speedup vs baseline: 3.6128x; 1.1603x over previous
//
#include <hip/hip_runtime.h>

#define N_V  20000
#define B_   8
#define F_   64
#define K_   6
#define OUT_ 64
#define NNZ_ 320000
#define BF   512    // B_*F_
#define NSLICE 8
#define SLICE_W 2500
#define NBUK (N_V * NSLICE)        // 160000 buckets
#define SCANB 157                  // ceil(NBUK/1024)

typedef unsigned short ushort_t;
typedef unsigned int   uint_t;

using frag_ab = __attribute__((ext_vector_type(8))) short;  // 8 bf16 (4 VGPRs)
using frag_cd = __attribute__((ext_vector_type(4))) float;  // 4 f32 acc

// ---- bf16 helpers ----
__device__ __forceinline__ ushort_t f2bf(float f) {          // round-to-nearest-even
    uint_t u = __float_as_uint(f);
    u += 0x7FFFu + ((u >> 16) & 1u);
    return (ushort_t)(u >> 16);
}
__device__ __forceinline__ uint_t pack2(float lo, float hi) {
    return (uint_t)f2bf(lo) | ((uint_t)f2bf(hi) << 16);
}
__device__ __forceinline__ void unpack2(uint_t u, float& lo, float& hi) {
    lo = __uint_as_float(u << 16);
    hi = __uint_as_float(u & 0xFFFF0000u);
}
__device__ __forceinline__ void unpack8(uint4 u, float* e) {
    unpack2(u.x, e[0], e[1]); unpack2(u.y, e[2], e[3]);
    unpack2(u.z, e[4], e[5]); unpack2(u.w, e[6], e[7]);
}

// ---------------- bucketed CSR build: key = row*8 + col/2500 ----------------

__global__ void hist_kernel(const int* __restrict__ rows, const int* __restrict__ cols,
                            int* __restrict__ counts) {
    int e = blockIdx.x * 256 + threadIdx.x;
    if (e < NNZ_) {
        int key = rows[e] * NSLICE + cols[e] / SLICE_W;
        atomicAdd(&counts[key], 1);
    }
}

// hierarchical scan over NBUK entries
__global__ __launch_bounds__(1024) void scan1(const int* __restrict__ counts,
                                              int* __restrict__ incl, int* __restrict__ bsum) {
    __shared__ int buf[1024];
    int tid = threadIdx.x;
    int i = blockIdx.x * 1024 + tid;
    int c = (i < NBUK) ? counts[i] : 0;
    buf[tid] = c;
    __syncthreads();
    for (int off = 1; off < 1024; off <<= 1) {
        int t = buf[tid];
        int add = (tid >= off) ? buf[tid - off] : 0;
        __syncthreads();
        buf[tid] = t + add;
        __syncthreads();
    }
    if (i < NBUK) incl[i] = buf[tid];
    if (tid == 1023) bsum[blockIdx.x] = buf[1023];
}

__global__ __launch_bounds__(256) void scan2(int* __restrict__ bsum) {
    __shared__ int buf[256];
    int tid = threadIdx.x;
    int c = (tid < SCANB) ? bsum[tid] : 0;
    buf[tid] = c;
    __syncthreads();
    for (int off = 1; off < 256; off <<= 1) {
        int t = buf[tid];
        int add = (tid >= off) ? buf[tid - off] : 0;
        __syncthreads();
        buf[tid] = t + add;
        __syncthreads();
    }
    if (tid < SCANB) bsum[tid] = buf[tid] - c;   // exclusive block offsets
}

// cursor holds per-chunk inclusive on entry; overwritten with bucket start.
__global__ __launch_bounds__(1024) void scan3(const int* __restrict__ counts,
                                              const int* __restrict__ bsum,
                                              int* __restrict__ bp, int* __restrict__ cursor) {
    int tid = threadIdx.x;
    int i = blockIdx.x * 1024 + tid;
    if (i < NBUK) {
        int p = bsum[blockIdx.x] + cursor[i];   // global inclusive prefix
        bp[i + 1] = p;
        cursor[i] = p - counts[i];              // bucket start for scatter
    }
    if (i == 0) bp[0] = 0;
}

__global__ void scatter_kernel(const int* __restrict__ rows, const int* __restrict__ cols,
                               const float* __restrict__ vals, int* __restrict__ cursor,
                               int* __restrict__ cols_perm, float* __restrict__ vals_perm) {
    int e = blockIdx.x * 256 + threadIdx.x;
    if (e < NNZ_) {
        int c = cols[e];
        int key = rows[e] * NSLICE + c / SLICE_W;
        int pos = atomicAdd(&cursor[key], 1);
        cols_perm[pos] = c;
        vals_perm[pos] = vals[e];
    }
}

// ---------------- x -> X0 (bf16, T layout: X0[n*512 + b*64 + f]) ----------------
__global__ void x2bf_kernel(const float* __restrict__ x, uint_t* __restrict__ X0) {
    int idx = blockIdx.x * 256 + threadIdx.x;   // exactly N_V*B_*32
    int f2 = idx & 31;
    int b  = (idx >> 5) & 7;
    int n  = idx >> 8;
    float2 v = *(const float2*)&x[((size_t)b * N_V + n) * F_ + f2 * 2];
    X0[n * 256 + b * 32 + f2] = pack2(v.x, v.y);
}

// ---------------- column-phased Chebyshev SpMM ----------------
// Block = 4 waves, wave owns 4 rows. Slices outer (phase-locked across grid),
// rows inner, acc in registers. Gathers per slice hit a 2.5 MB window -> L2.
template <bool RECUR>
__global__ __launch_bounds__(256) void cheb_phase(const int* __restrict__ bp,
                                                  const int* __restrict__ cols_perm,
                                                  const float* __restrict__ vals_perm,
                                                  const ushort_t* __restrict__ Tprev,
                                                  const ushort_t* __restrict__ Tpp,
                                                  ushort_t* __restrict__ Tout) {
    const int wave = threadIdx.x >> 6, lane = threadIdx.x & 63;
    const int n0 = blockIdx.x * 16 + wave * 4;
    float acc[4][8];
#pragma unroll
    for (int r = 0; r < 4; ++r)
#pragma unroll
        for (int i = 0; i < 8; ++i) acc[r][i] = 0.f;

    for (int s = 0; s < NSLICE; ++s) {
#pragma unroll
        for (int r = 0; r < 4; ++r) {
            const int bidx = (n0 + r) * NSLICE + s;
            int st = bp[bidx], en = bp[bidx + 1];
            for (int j = st; j < en; j += 2) {
                int j1 = j + 1;
                int jc1 = j1 < (NNZ_ - 1) ? j1 : (NNZ_ - 1);
                int   c0 = cols_perm[j];
                int   c1 = cols_perm[jc1];
                float v0 = vals_perm[j];
                float v1 = (j1 < en) ? vals_perm[jc1] : 0.f;
                uint4 u0 = *(const uint4*)(Tprev + (size_t)c0 * BF + lane * 8);
                uint4 u1 = *(const uint4*)(Tprev + (size_t)c1 * BF + lane * 8);
                float e0[8], e1[8];
                unpack8(u0, e0);
                unpack8(u1, e1);
#pragma unroll
                for (int i = 0; i < 8; ++i) {
                    acc[r][i] = fmaf(v0, e0[i], acc[r][i]);
                    acc[r][i] = fmaf(v1, e1[i], acc[r][i]);
                }
            }
        }
    }

#pragma unroll
    for (int r = 0; r < 4; ++r) {
        const int n = n0 + r;
        float res[8];
        if (RECUR) {
            uint4 up = *(const uint4*)(Tpp + (size_t)n * BF + lane * 8);
            float ep[8];
            unpack8(up, ep);
#pragma unroll
            for (int i = 0; i < 8; ++i) res[i] = 2.f * acc[r][i] - ep[i];
        } else {
#pragma unroll
            for (int i = 0; i < 8; ++i) res[i] = acc[r][i];
        }
        uint4 st;
        st.x = pack2(res[0], res[1]);
        st.y = pack2(res[2], res[3]);
        st.z = pack2(res[4], res[5]);
        st.w = pack2(res[6], res[7]);
        *(uint4*)(Tout + (size_t)n * BF + lane * 8) = st;
    }
}

// ---------------- Wfrag: W packed in MFMA B-fragment lane order ----------------
__global__ void wfrag_kernel(const float* __restrict__ W, ushort_t* __restrict__ Wfrag) {
    int idx = blockIdx.x * 256 + threadIdx.x;   // 0..24575
    if (idx < 12 * 4 * 64 * 8) {
        int j    = idx & 7;
        int lane = (idx >> 3) & 63;
        int ct   = (idx >> 9) & 3;
        int s    = idx >> 11;
        int o     = ct * 16 + (lane & 15);
        int kglob = s * 32 + ((lane >> 4) & 3) * 8 + j;
        Wfrag[idx] = f2bf(W[o * (K_ * F_) + kglob]);
    }
}

// ---------------- FC via MFMA 16x16x32 bf16, A = [X0|T1..T5] ----------------
__global__ __launch_bounds__(256) void fc_mfma(const ushort_t* __restrict__ X0,
                                               const ushort_t* __restrict__ T1,
                                               const ushort_t* __restrict__ T2,
                                               const ushort_t* __restrict__ T3,
                                               const ushort_t* __restrict__ T4,
                                               const ushort_t* __restrict__ T5,
                                               const ushort_t* __restrict__ Wfrag,
                                               const float* __restrict__ bias,
                                               float* __restrict__ out) {
    const int wave = threadIdx.x >> 6, lane = threadIdx.x & 63;
    const int quad = lane >> 4, col = lane & 15;
    const int tb = blockIdx.x * 64 + wave * 16;
    const int r = tb + col;                           // A row (m = lane&15)
    const ushort_t* Tbuf[6] = {X0, T1, T2, T3, T4, T5};

    frag_cd acc[4];
#pragma unroll
    for (int ct = 0; ct < 4; ++ct) acc[ct] = (frag_cd){0.f, 0.f, 0.f, 0.f};

#pragma unroll
    for (int s = 0; s < 12; ++s) {
        const int f0 = (s & 1) * 32 + quad * 8;
        frag_ab a = *(const frag_ab*)(Tbuf[s >> 1] + (size_t)r * F_ + f0);
#pragma unroll
        for (int ct = 0; ct < 4; ++ct) {
            frag_ab bfr = *(const frag_ab*)(Wfrag + (((s * 4 + ct) * 64 + lane) << 3));
            acc[ct] = __builtin_amdgcn_mfma_f32_16x16x32_bf16(a, bfr, acc[ct], 0, 0, 0);
        }
    }

    // C/D: col = lane&15, row = quad*4 + reg
#pragma unroll
    for (int ct = 0; ct < 4; ++ct) {
        const int o = ct * 16 + col;
        const float bv = bias[o];
#pragma unroll
        for (int reg = 0; reg < 4; ++reg) {
            int rr = tb + quad * 4 + reg;
            int nn = rr >> 3, bb = rr & 7;
            out[(size_t)bb * N_V * OUT_ + (size_t)nn * OUT_ + o] = acc[ct][reg] + bv;
        }
    }
}

// ---------------- launcher ----------------

extern "C" void kernel_launch(void* const* d_in, const int* in_sizes, int n_in,
                              void* d_out, int out_size, void* d_ws, size_t ws_size,
                              hipStream_t stream) {
    const float* x    = (const float*)d_in[0];
    const int*   rows = (const int*)  d_in[1];
    const int*   cols = (const int*)  d_in[2];
    const float* vals = (const float*)d_in[3];
    const float* W    = (const float*)d_in[4];
    const float* bias = (const float*)d_in[5];
    float* out = (float*)d_out;

    const size_t TSZ = (size_t)N_V * BF;           // bf16 elements per T buffer
    ushort_t* T1 = (ushort_t*)d_ws;
    ushort_t* T2 = T1 + TSZ;
    ushort_t* T3 = T2 + TSZ;
    ushort_t* T4 = T3 + TSZ;
    ushort_t* T5 = T4 + TSZ;
    ushort_t* X0 = T5 + TSZ;
    ushort_t* Wfrag = X0 + TSZ;                    // 24576 ushorts
    int* counts    = (int*)(Wfrag + 24576);        // NBUK
    int* bp        = counts + NBUK;                // NBUK+1 (+pad)
    int* cursor    = bp + NBUK + 64;               // NBUK
    int* bsum      = cursor + NBUK;                // 256
    int* cols_perm = bsum + 256;                   // NNZ
    float* vals_perm = (float*)(cols_perm + NNZ_); // NNZ

    hipMemsetAsync(counts, 0, NBUK * sizeof(int), stream);
    hist_kernel<<<(NNZ_ + 255) / 256, 256, 0, stream>>>(rows, cols, counts);
    scan1<<<SCANB, 1024, 0, stream>>>(counts, cursor, bsum);
    scan2<<<1, 256, 0, stream>>>(bsum);
    scan3<<<SCANB, 1024, 0, stream>>>(counts, bsum, bp, cursor);
    scatter_kernel<<<(NNZ_ + 255) / 256, 256, 0, stream>>>(rows, cols, vals, cursor,
                                                           cols_perm, vals_perm);
    x2bf_kernel<<<(N_V * B_ * 32) / 256, 256, 0, stream>>>(x, (uint_t*)X0);
    wfrag_kernel<<<96, 256, 0, stream>>>(W, Wfrag);

    cheb_phase<false><<<N_V / 16, 256, 0, stream>>>(bp, cols_perm, vals_perm, X0, nullptr, T1);
    cheb_phase<true ><<<N_V / 16, 256, 0, stream>>>(bp, cols_perm, vals_perm, T1, X0, T2);
    cheb_phase<true ><<<N_V / 16, 256, 0, stream>>>(bp, cols_perm, vals_perm, T2, T1, T3);
    cheb_phase<true ><<<N_V / 16, 256, 0, stream>>>(bp, cols_perm, vals_perm, T3, T2, T4);
    cheb_phase<true ><<<N_V / 16, 256, 0, stream>>>(bp, cols_perm, vals_perm, T4, T3, T5);

    fc_mfma<<<(N_V * B_) / 64, 256, 0, stream>>>(X0, T1, T2, T3, T4, T5, Wfrag, bias, out);
}